// Round 8
// baseline (185.066 us; speedup 1.0000x reference)
//
#include <hip/hip_runtime.h>

#define N_NODES 100000
#define N_EDGES 6400000
#define D_IN 256
constexpr float NEG_SLOPE = 0.2f;

#define NR 16           // node ranges
#define RANGE 6250      // nodes per range (N_NODES / NR)
#define NG 32           // partial groups per range (gather blocks per range)

// bucket path
#define NCH 1280        // edge chunks (bucket blocks)
#define CHE 5000        // edges per chunk
#define CAP 416         // segment capacity; mean 312.5, sigma 17.1 -> ~6 sigma
#define HALFCAP 208     // CAP/2 (pairs per segment)
#define CPG 40          // chunks per gather group (NCH / NG)
#define BBLK 256
#define CBLK 1024

// fallback scan path
#define FCHE 200000     // edges per chunk (32 chunks)

// ws layout (floats):
// [0, 2N)   xl   [N,2]
// [2N, 4N)  xr   [N,2]
// [4N, +9.6M)   partial [NR*NG][RANGE*3]
// bucket path after partial: recs [NCH*NR][CAP] float2, counts[NCH*NR] int, flag int
// scan path after partial:   flag int

// One wave per node: coalesced float4 row load, butterfly reduce.
__global__ void node_transform(const float* __restrict__ x,
                               const float* __restrict__ Wl, const float* __restrict__ bl,
                               const float* __restrict__ Wr, const float* __restrict__ br,
                               float* __restrict__ xl, float* __restrict__ xr) {
    int wave = (blockIdx.x * blockDim.x + threadIdx.x) >> 6;
    int lane = threadIdx.x & 63;
    if (wave >= N_NODES) return;
    const float4 xv  = *reinterpret_cast<const float4*>(x + (size_t)wave * D_IN + lane * 4);
    const float4 wlA = *reinterpret_cast<const float4*>(Wl + lane * 8);
    const float4 wlB = *reinterpret_cast<const float4*>(Wl + lane * 8 + 4);
    const float4 wrA = *reinterpret_cast<const float4*>(Wr + lane * 8);
    const float4 wrB = *reinterpret_cast<const float4*>(Wr + lane * 8 + 4);
    float sl0 = xv.x*wlA.x + xv.y*wlA.z + xv.z*wlB.x + xv.w*wlB.z;
    float sl1 = xv.x*wlA.y + xv.y*wlA.w + xv.z*wlB.y + xv.w*wlB.w;
    float sr0 = xv.x*wrA.x + xv.y*wrA.z + xv.z*wrB.x + xv.w*wrB.z;
    float sr1 = xv.x*wrA.y + xv.y*wrA.w + xv.z*wrB.y + xv.w*wrB.w;
    #pragma unroll
    for (int o = 32; o > 0; o >>= 1) {
        sl0 += __shfl_xor(sl0, o);
        sl1 += __shfl_xor(sl1, o);
        sr0 += __shfl_xor(sr0, o);
        sr1 += __shfl_xor(sr1, o);
    }
    if (lane == 0) {
        xl[2*wave]   = sl0 + bl[0];
        xl[2*wave+1] = sl1 + bl[1];
        xr[2*wave]   = sr0 + br[0];
        xr[2*wave+1] = sr1 + br[1];
    }
}

// Detect int64 vs int32 edge_index (int64 values < 2^17 => all odd words zero).
__global__ void detect_dtype(const int* __restrict__ ei32, int* __restrict__ flag) {
    int lane = threadIdx.x;  // 64 threads
    int v = ei32[2 * lane + 1];
    unsigned long long nz = __ballot(v != 0);
    if (lane == 0) *flag = (nz == 0ull) ? 1 : 0;
}

// ---------------- bucket path ----------------

// Pass B: pure streaming, no gathers, no math. Pack {src|li<<17, ea} into
// per-(chunk,range) segment via LDS slot counter. 4-wide vectorized loads.
__device__ __forceinline__ void bucket_one(int src, int tgt, float ea,
                                           float2* __restrict__ recs,
                                           int* __restrict__ cnt, int c) {
    const int r  = tgt / RANGE;
    const int li = tgt - r * RANGE;           // < 6250 -> 13 bits
    const int slot = atomicAdd(&cnt[r], 1);
    if (slot < CAP) {
        float2 rec;
        rec.x = __uint_as_float((unsigned)src | ((unsigned)li << 17));
        rec.y = ea;
        recs[(size_t)(c * NR + r) * CAP + slot] = rec;
    }
}

template <bool IS64>
__device__ __forceinline__ void bucket_loop(const void* __restrict__ ei,
                                            const float* __restrict__ eattr,
                                            float2* __restrict__ recs,
                                            int* __restrict__ cnt, int c) {
    const int base = c * CHE;
    const int end  = base + CHE;
    for (int j = 0; j < CHE; j += BBLK * 4) {
        const int e0 = base + j + (int)threadIdx.x * 4;
        if (e0 + 4 <= end) {
            int4 sv, tv;
            if (IS64) {
                const int4* ps = (const int4*)((const long long*)ei + e0);
                int4 a = ps[0], b = ps[1];
                sv = make_int4(a.x, a.z, b.x, b.z);
                const int4* pt = (const int4*)((const long long*)ei + N_EDGES + e0);
                int4 cc = pt[0], dd = pt[1];
                tv = make_int4(cc.x, cc.z, dd.x, dd.z);
            } else {
                sv = *(const int4*)((const int*)ei + e0);
                tv = *(const int4*)((const int*)ei + N_EDGES + e0);
            }
            const float4 ev = *(const float4*)(eattr + e0);
            bucket_one(sv.x, tv.x, ev.x, recs, cnt, c);
            bucket_one(sv.y, tv.y, ev.y, recs, cnt, c);
            bucket_one(sv.z, tv.z, ev.z, recs, cnt, c);
            bucket_one(sv.w, tv.w, ev.w, recs, cnt, c);
        } else if (e0 < end) {
            for (int e = e0; e < end && e < e0 + 4; ++e) {
                int src, tgt;
                if (IS64) { src = (int)((const long long*)ei)[e]; tgt = (int)((const long long*)ei)[N_EDGES + e]; }
                else      { src = ((const int*)ei)[e];            tgt = ((const int*)ei)[N_EDGES + e]; }
                bucket_one(src, tgt, eattr[e], recs, cnt, c);
            }
        }
    }
}

__global__ __launch_bounds__(BBLK) void bucket_pass(const void* __restrict__ ei,
                                                    const float* __restrict__ eattr,
                                                    float2* __restrict__ recs,
                                                    int* __restrict__ counts,
                                                    const int* __restrict__ flag) {
    __shared__ int cnt[NR];
    const int c = blockIdx.x;
    if (threadIdx.x < NR) cnt[threadIdx.x] = 0;
    __syncthreads();
    if (*flag) bucket_loop<true >(ei, eattr, recs, cnt, c);
    else       bucket_loop<false>(ei, eattr, recs, cnt, c);
    __syncthreads();
    if (threadIdx.x < NR) {
        int v = cnt[threadIdx.x];
        counts[c * NR + threadIdx.x] = v < CAP ? v : CAP;
    }
}

// Pass C: xr slice staged in LDS (only xl remains an L2 gather).
__global__ __launch_bounds__(CBLK) void gather_accum(const float2* __restrict__ recs,
                                                     const int* __restrict__ counts,
                                                     const float* __restrict__ xl,
                                                     const float* __restrict__ xr,
                                                     const float* __restrict__ We,
                                                     const float* __restrict__ att,
                                                     float* __restrict__ partial) {
    __shared__ float acc[RANGE * 3];     // 75 KB
    __shared__ float2 xrs[RANGE];        // 50 KB
    __shared__ int s_n[CPG];
    const int r = blockIdx.x & (NR - 1);
    const int g = blockIdx.x >> 4;
    const int lo = r * RANGE;
    const float2* xr2 = (const float2*)xr;
    for (int i = threadIdx.x; i < RANGE * 3; i += CBLK) acc[i] = 0.f;
    for (int i = threadIdx.x; i < RANGE; i += CBLK) xrs[i] = xr2[lo + i];
    if (threadIdx.x < CPG)
        s_n[threadIdx.x] = counts[(g * CPG + threadIdx.x) * NR + r];
    __syncthreads();
    const float we0 = We[0], we1 = We[1];
    const float a0 = att[0], a1 = att[1];
    const float2* xl2 = (const float2*)xl;
    const int c0 = g * CPG;

    for (int idx = threadIdx.x; idx < CPG * HALFCAP; idx += CBLK) {
        const int cc = idx / HALFCAP;
        const int i  = idx - cc * HALFCAP;
        const int n  = s_n[cc];
        if (i < (n >> 1)) {
            const float2* seg = recs + (size_t)((c0 + cc) * NR + r) * CAP;
            const float4 two = ((const float4*)seg)[i];
            // decode both, issue both gathers before any math/atomics
            const unsigned p0 = __float_as_uint(two.x);
            const unsigned p1 = __float_as_uint(two.z);
            const int s0 = p0 & 0x1FFFF, l0 = p0 >> 17;
            const int s1 = p1 & 0x1FFFF, l1 = p1 >> 17;
            const float2 xs0 = xl2[s0];
            const float2 xs1 = xl2[s1];
            const float2 xt0 = xrs[l0];
            const float2 xt1 = xrs[l1];
            float m00 = xs0.x + xt0.x + two.y * we0;
            float m01 = xs0.y + xt0.y + two.y * we1;
            float m10 = xs1.x + xt1.x + two.w * we0;
            float m11 = xs1.y + xt1.y + two.w * we1;
            m00 = m00 > 0.f ? m00 : NEG_SLOPE * m00;
            m01 = m01 > 0.f ? m01 : NEG_SLOPE * m01;
            m10 = m10 > 0.f ? m10 : NEG_SLOPE * m10;
            m11 = m11 > 0.f ? m11 : NEG_SLOPE * m11;
            const float ex0 = __expf(m00 * a0 + m01 * a1);
            const float ex1 = __expf(m10 * a0 + m11 * a1);
            float* b0 = acc + l0 * 3;
            atomicAdd(b0 + 0, ex0 * xs0.x);
            atomicAdd(b0 + 1, ex0 * xs0.y);
            atomicAdd(b0 + 2, ex0);
            float* b1 = acc + l1 * 3;
            atomicAdd(b1 + 0, ex1 * xs1.x);
            atomicAdd(b1 + 1, ex1 * xs1.y);
            atomicAdd(b1 + 2, ex1);
        }
    }
    // odd-count tails, one thread per chunk (wave-parallel)
    if (threadIdx.x < CPG) {
        const int n = s_n[threadIdx.x];
        if (n & 1) {
            const float2* seg = recs + (size_t)((c0 + threadIdx.x) * NR + r) * CAP;
            const float2 rec = seg[n - 1];
            const unsigned p = __float_as_uint(rec.x);
            const int s = p & 0x1FFFF, l = p >> 17;
            const float2 xs = xl2[s];
            const float2 xt = xrs[l];
            float m0 = xs.x + xt.x + rec.y * we0;
            float m1 = xs.y + xt.y + rec.y * we1;
            m0 = m0 > 0.f ? m0 : NEG_SLOPE * m0;
            m1 = m1 > 0.f ? m1 : NEG_SLOPE * m1;
            const float ex = __expf(m0 * a0 + m1 * a1);
            float* b = acc + l * 3;
            atomicAdd(b + 0, ex * xs.x);
            atomicAdd(b + 1, ex * xs.y);
            atomicAdd(b + 2, ex);
        }
    }
    __syncthreads();
    float* dst = partial + (size_t)(r * NG + g) * (RANGE * 3);
    for (int i = threadIdx.x; i < RANGE * 3; i += CBLK) dst[i] = acc[i];
}

// ---------------- fallback scan path ----------------
template <bool IS64>
__device__ __forceinline__ void scan_loop(const void* __restrict__ ei,
                                          const float* __restrict__ eattr,
                                          const float2* __restrict__ xl2,
                                          const float2* __restrict__ xr2,
                                          float we0, float we1, float a0, float a1,
                                          int lo, int eBeg, int eEnd,
                                          float* __restrict__ acc) {
    for (int e = eBeg + (int)threadIdx.x; e < eEnd; e += CBLK) {
        int tgt;
        if (IS64) tgt = (int)((const long long*)ei)[N_EDGES + e];
        else      tgt = ((const int*)ei)[N_EDGES + e];
        unsigned li = (unsigned)(tgt - lo);
        if (li < RANGE) {
            int src;
            if (IS64) src = (int)((const long long*)ei)[e];
            else      src = ((const int*)ei)[e];
            const float ea = eattr[e];
            const float2 xs = xl2[src];
            const float2 xt = xr2[tgt];
            float m0 = xs.x + xt.x + ea * we0;
            float m1 = xs.y + xt.y + ea * we1;
            m0 = m0 > 0.f ? m0 : NEG_SLOPE * m0;
            m1 = m1 > 0.f ? m1 : NEG_SLOPE * m1;
            const float ex = __expf(m0 * a0 + m1 * a1);
            float* b = acc + li * 3u;
            atomicAdd(b + 0, ex * xs.x);
            atomicAdd(b + 1, ex * xs.y);
            atomicAdd(b + 2, ex);
        }
    }
}

__global__ __launch_bounds__(CBLK) void edge_scan(const void* __restrict__ ei,
                                                  const float* __restrict__ eattr,
                                                  const float* __restrict__ xl,
                                                  const float* __restrict__ xr,
                                                  const float* __restrict__ We,
                                                  const float* __restrict__ att,
                                                  float* __restrict__ partial,
                                                  const int* __restrict__ flag) {
    __shared__ float acc[RANGE * 3];
    const int r = blockIdx.x & (NR - 1);
    const int g = blockIdx.x >> 4;          // 32 chunks
    for (int i = threadIdx.x; i < RANGE * 3; i += CBLK) acc[i] = 0.f;
    __syncthreads();
    const int lo = r * RANGE;
    const int eBeg = g * FCHE, eEnd = eBeg + FCHE;
    const float we0 = We[0], we1 = We[1];
    const float a0 = att[0], a1 = att[1];
    if (*flag)
        scan_loop<true >(ei, eattr, (const float2*)xl, (const float2*)xr, we0, we1, a0, a1, lo, eBeg, eEnd, acc);
    else
        scan_loop<false>(ei, eattr, (const float2*)xl, (const float2*)xr, we0, we1, a0, a1, lo, eBeg, eEnd, acc);
    __syncthreads();
    float* dst = partial + (size_t)(r * NG + g) * (RANGE * 3);
    for (int i = threadIdx.x; i < RANGE * 3; i += CBLK) dst[i] = acc[i];
}
// ---------------------------------------------------------------------

// Sum the NG group-partials per node, normalize, add bias.
__global__ void reduce_partials(const float* __restrict__ partial,
                                const float* __restrict__ bias, float* __restrict__ out) {
    int i = blockIdx.x * blockDim.x + threadIdx.x;
    if (i >= N_NODES) return;
    const int r = i / RANGE;
    const int li = i - r * RANGE;
    float n0 = 0.f, n1 = 0.f, d = 0.f;
    #pragma unroll 4
    for (int g = 0; g < NG; ++g) {
        const float* p = partial + (size_t)(r * NG + g) * (RANGE * 3) + (size_t)li * 3;
        n0 += p[0]; n1 += p[1]; d += p[2];
    }
    d += 1e-16f;
    float2 o;
    o.x = n0 / d + bias[0];
    o.y = n1 / d + bias[1];
    ((float2*)out)[i] = o;
}

// last-resort atomic path
__global__ void edge_pass_atomic(const void* __restrict__ ei,
                                 const float* __restrict__ eattr,
                                 const float* __restrict__ xl, const float* __restrict__ xr,
                                 const float* __restrict__ We, const float* __restrict__ att,
                                 float* __restrict__ acc4, const int* __restrict__ flag) {
    const int is64 = *flag;
    const float we0 = We[0], we1 = We[1];
    const float a0 = att[0], a1 = att[1];
    const int stride = gridDim.x * blockDim.x;
    for (int e = blockIdx.x * blockDim.x + threadIdx.x; e < N_EDGES; e += stride) {
        int src, tgt;
        if (is64) { src = (int)((const long long*)ei)[e]; tgt = (int)((const long long*)ei)[N_EDGES + e]; }
        else      { src = ((const int*)ei)[e];            tgt = ((const int*)ei)[N_EDGES + e]; }
        const float ea = eattr[e];
        const float2 xs = ((const float2*)xl)[src];
        const float2 xt = ((const float2*)xr)[tgt];
        float m0 = xs.x + xt.x + ea * we0;
        float m1 = xs.y + xt.y + ea * we1;
        m0 = m0 > 0.f ? m0 : NEG_SLOPE * m0;
        m1 = m1 > 0.f ? m1 : NEG_SLOPE * m1;
        const float ex = __expf(m0 * a0 + m1 * a1);
        float* b = acc4 + (size_t)tgt * 4;
        atomicAdd(b + 0, ex * xs.x);
        atomicAdd(b + 1, ex * xs.y);
        atomicAdd(b + 2, ex);
    }
}

__global__ void finalize4(const float* __restrict__ acc4,
                          const float* __restrict__ bias, float* __restrict__ out) {
    int i = blockIdx.x * blockDim.x + threadIdx.x;
    if (i >= N_NODES) return;
    const float4 a = ((const float4*)acc4)[i];
    const float d = a.z + 1e-16f;
    float2 o;
    o.x = a.x / d + bias[0];
    o.y = a.y / d + bias[1];
    ((float2*)out)[i] = o;
}

extern "C" void kernel_launch(void* const* d_in, const int* in_sizes, int n_in,
                              void* d_out, int out_size, void* d_ws, size_t ws_size,
                              hipStream_t stream) {
    const float* x    = (const float*)d_in[0];
    const void*  ei   = d_in[1];
    const float* ea   = (const float*)d_in[2];
    const float* Wl   = (const float*)d_in[3];
    const float* bl   = (const float*)d_in[4];
    const float* Wr   = (const float*)d_in[5];
    const float* br   = (const float*)d_in[6];
    const float* We   = (const float*)d_in[7];
    const float* att  = (const float*)d_in[8];
    const float* bias = (const float*)d_in[9];

    float* ws      = (float*)d_ws;
    float* xl      = ws;
    float* xr      = ws + 2 * N_NODES;
    float* partial = ws + 4 * N_NODES;                       // [NR*NG][RANGE*3]
    const size_t partial_floats = (size_t)NR * NG * RANGE * 3;
    float* recs_f  = partial + partial_floats;               // [NCH*NR][CAP] float2
    const size_t recs_floats = (size_t)NCH * NR * CAP * 2;
    int*   counts  = (int*)(recs_f + recs_floats);           // [NCH*NR]

    const size_t need_bucket = (4 * (size_t)N_NODES + partial_floats + recs_floats
                                + (size_t)NCH * NR + 16) * sizeof(float);
    const size_t need_scan   = (4 * (size_t)N_NODES + partial_floats + 16) * sizeof(float);

    node_transform<<<(N_NODES * 64) / 256, 256, 0, stream>>>(x, Wl, bl, Wr, br, xl, xr);

    if (ws_size >= need_bucket) {
        int* flag = counts + (size_t)NCH * NR;
        detect_dtype<<<1, 64, 0, stream>>>((const int*)ei, flag);
        bucket_pass<<<NCH, BBLK, 0, stream>>>(ei, ea, (float2*)recs_f, counts, flag);
        gather_accum<<<NR * NG, CBLK, 0, stream>>>((const float2*)recs_f, counts,
                                                   xl, xr, We, att, partial);
        reduce_partials<<<(N_NODES + 255) / 256, 256, 0, stream>>>(partial, bias, (float*)d_out);
    } else if (ws_size >= need_scan) {
        int* flag = (int*)(partial + partial_floats);
        detect_dtype<<<1, 64, 0, stream>>>((const int*)ei, flag);
        edge_scan<<<NR * NG, CBLK, 0, stream>>>(ei, ea, xl, xr, We, att, partial, flag);
        reduce_partials<<<(N_NODES + 255) / 256, 256, 0, stream>>>(partial, bias, (float*)d_out);
    } else {
        float* acc4 = ws + 4 * N_NODES;
        int* flag = (int*)(acc4 + 4 * (size_t)N_NODES);
        hipMemsetAsync(acc4, 0, (size_t)N_NODES * 4 * sizeof(float), stream);
        detect_dtype<<<1, 64, 0, stream>>>((const int*)ei, flag);
        edge_pass_atomic<<<4096, 256, 0, stream>>>(ei, ea, xl, xr, We, att, acc4, flag);
        finalize4<<<(N_NODES + 255) / 256, 256, 0, stream>>>(acc4, bias, (float*)d_out);
    }
}

// Round 9
// 127.349 us; speedup vs baseline: 1.4532x; 1.4532x over previous
//
#include <hip/hip_runtime.h>

#define N_NODES 100000
#define N_EDGES 6400000
#define D_IN 256
constexpr float NEG_SLOPE = 0.2f;

#define NR 16           // node ranges
#define RANGE 6250      // nodes per range (N_NODES / NR)
#define NG 16           // partial groups per range (gather blocks per range)

// bucket path
#define NCH 1280        // edge chunks (bucket blocks)
#define CHE 5000        // edges per chunk
#define CAP 416         // segment capacity; mean 312.5, sigma 17.1 -> ~6 sigma
#define CPG 80          // chunks per gather group (NCH / NG)
#define FLAT (CPG * CAP)// flattened record-index space per gather block (33280)
#define BBLK 256
#define CBLK 1024

// fallback scan path
#define FCHE 400000     // edges per chunk (16 chunks)

// ws layout (floats):
// [0, 2N)   xl   [N,2]
// [2N, 4N)  xr   [N,2]
// [4N, +4.8M)   partial [NR*NG][RANGE*3]
// bucket path after partial: recs [NCH*NR][CAP] float2, counts[NCH*NR] int, flag int
// scan path after partial:   flag int

// One wave per node: coalesced float4 row load, butterfly reduce.
__global__ void node_transform(const float* __restrict__ x,
                               const float* __restrict__ Wl, const float* __restrict__ bl,
                               const float* __restrict__ Wr, const float* __restrict__ br,
                               float* __restrict__ xl, float* __restrict__ xr) {
    int wave = (blockIdx.x * blockDim.x + threadIdx.x) >> 6;
    int lane = threadIdx.x & 63;
    if (wave >= N_NODES) return;
    const float4 xv  = *reinterpret_cast<const float4*>(x + (size_t)wave * D_IN + lane * 4);
    const float4 wlA = *reinterpret_cast<const float4*>(Wl + lane * 8);
    const float4 wlB = *reinterpret_cast<const float4*>(Wl + lane * 8 + 4);
    const float4 wrA = *reinterpret_cast<const float4*>(Wr + lane * 8);
    const float4 wrB = *reinterpret_cast<const float4*>(Wr + lane * 8 + 4);
    float sl0 = xv.x*wlA.x + xv.y*wlA.z + xv.z*wlB.x + xv.w*wlB.z;
    float sl1 = xv.x*wlA.y + xv.y*wlA.w + xv.z*wlB.y + xv.w*wlB.w;
    float sr0 = xv.x*wrA.x + xv.y*wrA.z + xv.z*wrB.x + xv.w*wrB.z;
    float sr1 = xv.x*wrA.y + xv.y*wrA.w + xv.z*wrB.y + xv.w*wrB.w;
    #pragma unroll
    for (int o = 32; o > 0; o >>= 1) {
        sl0 += __shfl_xor(sl0, o);
        sl1 += __shfl_xor(sl1, o);
        sr0 += __shfl_xor(sr0, o);
        sr1 += __shfl_xor(sr1, o);
    }
    if (lane == 0) {
        xl[2*wave]   = sl0 + bl[0];
        xl[2*wave+1] = sl1 + bl[1];
        xr[2*wave]   = sr0 + br[0];
        xr[2*wave+1] = sr1 + br[1];
    }
}

// Detect int64 vs int32 edge_index (int64 values < 2^17 => all odd words zero).
__global__ void detect_dtype(const int* __restrict__ ei32, int* __restrict__ flag) {
    int lane = threadIdx.x;  // 64 threads
    int v = ei32[2 * lane + 1];
    unsigned long long nz = __ballot(v != 0);
    if (lane == 0) *flag = (nz == 0ull) ? 1 : 0;
}

// ---------------- bucket path ----------------

// Pass B: pure streaming, no gathers, no math. Pack {src|li<<17, ea} into
// per-(chunk,range) segment via LDS slot counter. 4-wide vectorized loads.
__device__ __forceinline__ void bucket_one(int src, int tgt, float ea,
                                           float2* __restrict__ recs,
                                           int* __restrict__ cnt, int c) {
    const int r  = tgt / RANGE;
    const int li = tgt - r * RANGE;           // < 6250 -> 13 bits
    const int slot = atomicAdd(&cnt[r], 1);
    if (slot < CAP) {
        float2 rec;
        rec.x = __uint_as_float((unsigned)src | ((unsigned)li << 17));
        rec.y = ea;
        recs[(size_t)(c * NR + r) * CAP + slot] = rec;
    }
}

template <bool IS64>
__device__ __forceinline__ void bucket_loop(const void* __restrict__ ei,
                                            const float* __restrict__ eattr,
                                            float2* __restrict__ recs,
                                            int* __restrict__ cnt, int c) {
    const int base = c * CHE;
    const int end  = base + CHE;
    for (int j = 0; j < CHE; j += BBLK * 4) {
        const int e0 = base + j + (int)threadIdx.x * 4;
        if (e0 + 4 <= end) {
            int4 sv, tv;
            if (IS64) {
                const int4* ps = (const int4*)((const long long*)ei + e0);
                int4 a = ps[0], b = ps[1];
                sv = make_int4(a.x, a.z, b.x, b.z);
                const int4* pt = (const int4*)((const long long*)ei + N_EDGES + e0);
                int4 cc = pt[0], dd = pt[1];
                tv = make_int4(cc.x, cc.z, dd.x, dd.z);
            } else {
                sv = *(const int4*)((const int*)ei + e0);
                tv = *(const int4*)((const int*)ei + N_EDGES + e0);
            }
            const float4 ev = *(const float4*)(eattr + e0);
            bucket_one(sv.x, tv.x, ev.x, recs, cnt, c);
            bucket_one(sv.y, tv.y, ev.y, recs, cnt, c);
            bucket_one(sv.z, tv.z, ev.z, recs, cnt, c);
            bucket_one(sv.w, tv.w, ev.w, recs, cnt, c);
        } else if (e0 < end) {
            for (int e = e0; e < end && e < e0 + 4; ++e) {
                int src, tgt;
                if (IS64) { src = (int)((const long long*)ei)[e]; tgt = (int)((const long long*)ei)[N_EDGES + e]; }
                else      { src = ((const int*)ei)[e];            tgt = ((const int*)ei)[N_EDGES + e]; }
                bucket_one(src, tgt, eattr[e], recs, cnt, c);
            }
        }
    }
}

__global__ __launch_bounds__(BBLK) void bucket_pass(const void* __restrict__ ei,
                                                    const float* __restrict__ eattr,
                                                    float2* __restrict__ recs,
                                                    int* __restrict__ counts,
                                                    const int* __restrict__ flag) {
    __shared__ int cnt[NR];
    const int c = blockIdx.x;
    if (threadIdx.x < NR) cnt[threadIdx.x] = 0;
    __syncthreads();
    if (*flag) bucket_loop<true >(ei, eattr, recs, cnt, c);
    else       bucket_loop<false>(ei, eattr, recs, cnt, c);
    __syncthreads();
    if (threadIdx.x < NR) {
        int v = cnt[threadIdx.x];
        counts[c * NR + threadIdx.x] = v < CAP ? v : CAP;
    }
}

// Pass C: claim/winner accumulation — one non-atomic RMW per node per batch;
// only colliding lanes (~8%) fall back to LDS atomics. Record loads software-
// pipelined one batch ahead.
__global__ __launch_bounds__(CBLK) void gather_accum(const float2* __restrict__ recs,
                                                     const int* __restrict__ counts,
                                                     const float* __restrict__ xl,
                                                     const float* __restrict__ xr,
                                                     const float* __restrict__ We,
                                                     const float* __restrict__ att,
                                                     float* __restrict__ partial) {
    __shared__ float  acc[RANGE * 3];   // 73.2 KB
    __shared__ float2 xrs[RANGE];       // 48.8 KB
    __shared__ int    tag[RANGE];       // 24.4 KB
    __shared__ int    s_n[CPG];
    const int r = blockIdx.x & (NR - 1);
    const int g = blockIdx.x >> 4;
    const int lo = r * RANGE;
    for (int i = threadIdx.x; i < RANGE * 3; i += CBLK) acc[i] = 0.f;
    for (int i = threadIdx.x; i < RANGE; i += CBLK) xrs[i] = ((const float2*)xr)[lo + i];
    for (int i = threadIdx.x; i < CPG; i += CBLK) s_n[i] = counts[(g * CPG + i) * NR + r];
    __syncthreads();
    const float we0 = We[0], we1 = We[1];
    const float a0 = att[0], a1 = att[1];
    const float2* xl2 = (const float2*)xl;
    const int c0 = g * CPG;
    const int tid = threadIdx.x;

    // prologue: load batch-0 record
    bool have;
    float2 rec;
    {
        const int idx = tid;
        have = false;
        rec = make_float2(0.f, 0.f);
        const int cc = idx / CAP;
        const int i  = idx - cc * CAP;
        if (i < s_n[cc]) {   // idx < FLAT always for batch 0
            have = true;
            rec = (recs + (size_t)((c0 + cc) * NR + r) * CAP)[i];
        }
    }

    for (int base = 0; base < FLAT; base += CBLK) {
        // compute current batch from prefetched record
        int li = 0;
        float ex = 0.f, cv0 = 0.f, cv1 = 0.f;
        const bool h = have;
        if (h) {
            const unsigned p = __float_as_uint(rec.x);
            const int s = p & 0x1FFFF;
            li = p >> 17;
            const float2 xs = xl2[s];
            const float2 xt = xrs[li];
            float m0 = xs.x + xt.x + rec.y * we0;
            float m1 = xs.y + xt.y + rec.y * we1;
            m0 = m0 > 0.f ? m0 : NEG_SLOPE * m0;
            m1 = m1 > 0.f ? m1 : NEG_SLOPE * m1;
            ex  = __expf(m0 * a0 + m1 * a1);
            cv0 = ex * xs.x;
            cv1 = ex * xs.y;
            tag[li] = tid;            // claim (non-atomic; one writer wins)
        }
        // prefetch next batch's record (overlaps barriers + phases)
        {
            const int idx = base + CBLK + tid;
            have = false;
            if (idx < FLAT) {
                const int cc = idx / CAP;
                const int i  = idx - cc * CAP;
                if (i < s_n[cc]) {
                    have = true;
                    rec = (recs + (size_t)((c0 + cc) * NR + r) * CAP)[i];
                }
            }
        }
        __syncthreads();
        bool win = false;
        if (h) {
            win = (tag[li] == tid);
            if (win) {                 // exclusive: plain RMW, no atomic
                float* b = acc + li * 3;
                b[0] += cv0;
                b[1] += cv1;
                b[2] += ex;
            }
        }
        __syncthreads();
        if (h && !win) {               // rare losers: atomic fallback
            float* b = acc + li * 3;
            atomicAdd(b + 0, cv0);
            atomicAdd(b + 1, cv1);
            atomicAdd(b + 2, ex);
        }
        __syncthreads();
    }

    float* dst = partial + (size_t)(r * NG + g) * (RANGE * 3);
    for (int i = threadIdx.x; i < RANGE * 3; i += CBLK) dst[i] = acc[i];
}

// ---------------- fallback scan path ----------------
template <bool IS64>
__device__ __forceinline__ void scan_loop(const void* __restrict__ ei,
                                          const float* __restrict__ eattr,
                                          const float2* __restrict__ xl2,
                                          const float2* __restrict__ xr2,
                                          float we0, float we1, float a0, float a1,
                                          int lo, int eBeg, int eEnd,
                                          float* __restrict__ acc) {
    for (int e = eBeg + (int)threadIdx.x; e < eEnd; e += CBLK) {
        int tgt;
        if (IS64) tgt = (int)((const long long*)ei)[N_EDGES + e];
        else      tgt = ((const int*)ei)[N_EDGES + e];
        unsigned li = (unsigned)(tgt - lo);
        if (li < RANGE) {
            int src;
            if (IS64) src = (int)((const long long*)ei)[e];
            else      src = ((const int*)ei)[e];
            const float ea = eattr[e];
            const float2 xs = xl2[src];
            const float2 xt = xr2[tgt];
            float m0 = xs.x + xt.x + ea * we0;
            float m1 = xs.y + xt.y + ea * we1;
            m0 = m0 > 0.f ? m0 : NEG_SLOPE * m0;
            m1 = m1 > 0.f ? m1 : NEG_SLOPE * m1;
            const float ex = __expf(m0 * a0 + m1 * a1);
            float* b = acc + li * 3u;
            atomicAdd(b + 0, ex * xs.x);
            atomicAdd(b + 1, ex * xs.y);
            atomicAdd(b + 2, ex);
        }
    }
}

__global__ __launch_bounds__(CBLK) void edge_scan(const void* __restrict__ ei,
                                                  const float* __restrict__ eattr,
                                                  const float* __restrict__ xl,
                                                  const float* __restrict__ xr,
                                                  const float* __restrict__ We,
                                                  const float* __restrict__ att,
                                                  float* __restrict__ partial,
                                                  const int* __restrict__ flag) {
    __shared__ float acc[RANGE * 3];
    const int r = blockIdx.x & (NR - 1);
    const int g = blockIdx.x >> 4;          // 16 chunks
    for (int i = threadIdx.x; i < RANGE * 3; i += CBLK) acc[i] = 0.f;
    __syncthreads();
    const int lo = r * RANGE;
    const int eBeg = g * FCHE, eEnd = eBeg + FCHE;
    const float we0 = We[0], we1 = We[1];
    const float a0 = att[0], a1 = att[1];
    if (*flag)
        scan_loop<true >(ei, eattr, (const float2*)xl, (const float2*)xr, we0, we1, a0, a1, lo, eBeg, eEnd, acc);
    else
        scan_loop<false>(ei, eattr, (const float2*)xl, (const float2*)xr, we0, we1, a0, a1, lo, eBeg, eEnd, acc);
    __syncthreads();
    float* dst = partial + (size_t)(r * NG + g) * (RANGE * 3);
    for (int i = threadIdx.x; i < RANGE * 3; i += CBLK) dst[i] = acc[i];
}
// ---------------------------------------------------------------------

// Sum the NG group-partials per node, normalize, add bias.
__global__ void reduce_partials(const float* __restrict__ partial,
                                const float* __restrict__ bias, float* __restrict__ out) {
    int i = blockIdx.x * blockDim.x + threadIdx.x;
    if (i >= N_NODES) return;
    const int r = i / RANGE;
    const int li = i - r * RANGE;
    float n0 = 0.f, n1 = 0.f, d = 0.f;
    #pragma unroll 4
    for (int g = 0; g < NG; ++g) {
        const float* p = partial + (size_t)(r * NG + g) * (RANGE * 3) + (size_t)li * 3;
        n0 += p[0]; n1 += p[1]; d += p[2];
    }
    d += 1e-16f;
    float2 o;
    o.x = n0 / d + bias[0];
    o.y = n1 / d + bias[1];
    ((float2*)out)[i] = o;
}

// last-resort atomic path
__global__ void edge_pass_atomic(const void* __restrict__ ei,
                                 const float* __restrict__ eattr,
                                 const float* __restrict__ xl, const float* __restrict__ xr,
                                 const float* __restrict__ We, const float* __restrict__ att,
                                 float* __restrict__ acc4, const int* __restrict__ flag) {
    const int is64 = *flag;
    const float we0 = We[0], we1 = We[1];
    const float a0 = att[0], a1 = att[1];
    const int stride = gridDim.x * blockDim.x;
    for (int e = blockIdx.x * blockDim.x + threadIdx.x; e < N_EDGES; e += stride) {
        int src, tgt;
        if (is64) { src = (int)((const long long*)ei)[e]; tgt = (int)((const long long*)ei)[N_EDGES + e]; }
        else      { src = ((const int*)ei)[e];            tgt = ((const int*)ei)[N_EDGES + e]; }
        const float ea = eattr[e];
        const float2 xs = ((const float2*)xl)[src];
        const float2 xt = ((const float2*)xr)[tgt];
        float m0 = xs.x + xt.x + ea * we0;
        float m1 = xs.y + xt.y + ea * we1;
        m0 = m0 > 0.f ? m0 : NEG_SLOPE * m0;
        m1 = m1 > 0.f ? m1 : NEG_SLOPE * m1;
        const float ex = __expf(m0 * a0 + m1 * a1);
        float* b = acc4 + (size_t)tgt * 4;
        atomicAdd(b + 0, ex * xs.x);
        atomicAdd(b + 1, ex * xs.y);
        atomicAdd(b + 2, ex);
    }
}

__global__ void finalize4(const float* __restrict__ acc4,
                          const float* __restrict__ bias, float* __restrict__ out) {
    int i = blockIdx.x * blockDim.x + threadIdx.x;
    if (i >= N_NODES) return;
    const float4 a = ((const float4*)acc4)[i];
    const float d = a.z + 1e-16f;
    float2 o;
    o.x = a.x / d + bias[0];
    o.y = a.y / d + bias[1];
    ((float2*)out)[i] = o;
}

extern "C" void kernel_launch(void* const* d_in, const int* in_sizes, int n_in,
                              void* d_out, int out_size, void* d_ws, size_t ws_size,
                              hipStream_t stream) {
    const float* x    = (const float*)d_in[0];
    const void*  ei   = d_in[1];
    const float* ea   = (const float*)d_in[2];
    const float* Wl   = (const float*)d_in[3];
    const float* bl   = (const float*)d_in[4];
    const float* Wr   = (const float*)d_in[5];
    const float* br   = (const float*)d_in[6];
    const float* We   = (const float*)d_in[7];
    const float* att  = (const float*)d_in[8];
    const float* bias = (const float*)d_in[9];

    float* ws      = (float*)d_ws;
    float* xl      = ws;
    float* xr      = ws + 2 * N_NODES;
    float* partial = ws + 4 * N_NODES;                       // [NR*NG][RANGE*3]
    const size_t partial_floats = (size_t)NR * NG * RANGE * 3;
    float* recs_f  = partial + partial_floats;               // [NCH*NR][CAP] float2
    const size_t recs_floats = (size_t)NCH * NR * CAP * 2;
    int*   counts  = (int*)(recs_f + recs_floats);           // [NCH*NR]

    const size_t need_bucket = (4 * (size_t)N_NODES + partial_floats + recs_floats
                                + (size_t)NCH * NR + 16) * sizeof(float);
    const size_t need_scan   = (4 * (size_t)N_NODES + partial_floats + 16) * sizeof(float);

    node_transform<<<(N_NODES * 64) / 256, 256, 0, stream>>>(x, Wl, bl, Wr, br, xl, xr);

    if (ws_size >= need_bucket) {
        int* flag = counts + (size_t)NCH * NR;
        detect_dtype<<<1, 64, 0, stream>>>((const int*)ei, flag);
        bucket_pass<<<NCH, BBLK, 0, stream>>>(ei, ea, (float2*)recs_f, counts, flag);
        gather_accum<<<NR * NG, CBLK, 0, stream>>>((const float2*)recs_f, counts,
                                                   xl, xr, We, att, partial);
        reduce_partials<<<(N_NODES + 255) / 256, 256, 0, stream>>>(partial, bias, (float*)d_out);
    } else if (ws_size >= need_scan) {
        int* flag = (int*)(partial + partial_floats);
        detect_dtype<<<1, 64, 0, stream>>>((const int*)ei, flag);
        edge_scan<<<NR * NG, CBLK, 0, stream>>>(ei, ea, xl, xr, We, att, partial, flag);
        reduce_partials<<<(N_NODES + 255) / 256, 256, 0, stream>>>(partial, bias, (float*)d_out);
    } else {
        float* acc4 = ws + 4 * N_NODES;
        int* flag = (int*)(acc4 + 4 * (size_t)N_NODES);
        hipMemsetAsync(acc4, 0, (size_t)N_NODES * 4 * sizeof(float), stream);
        detect_dtype<<<1, 64, 0, stream>>>((const int*)ei, flag);
        edge_pass_atomic<<<4096, 256, 0, stream>>>(ei, ea, xl, xr, We, att, acc4, flag);
        finalize4<<<(N_NODES + 255) / 256, 256, 0, stream>>>(acc4, bias, (float*)d_out);
    }
}

// Round 10
// 122.928 us; speedup vs baseline: 1.5055x; 1.0360x over previous
//
#include <hip/hip_runtime.h>

#define N_NODES 100000
#define N_EDGES 6400000
#define D_IN 256
constexpr float NEG_SLOPE = 0.2f;

#define NR 16           // node ranges
#define RANGE 6250      // nodes per range (N_NODES / NR)
#define NG 16           // partial groups per range (gather blocks per range)

// bucket path
#define NCH 1280        // edge chunks (bucket blocks)
#define CHE 5000        // edges per chunk
#define CAP 416         // segment capacity; mean 312.5, sigma 17.1 -> ~6 sigma
#define HALFCAP 208     // record pairs per segment
#define CPG 80          // chunks per gather group (NCH / NG)
#define PFLAT (CPG * HALFCAP)   // flattened PAIR-index space per gather block (16640)
#define NB ((PFLAT + 1023) / 1024)  // batches (17)
#define BBLK 256
#define CBLK 1024

// fallback scan path
#define FCHE 400000     // edges per chunk (16 chunks)

// ws layout (floats):
// [0, 2N)   xl   [N,2]
// [2N, 4N)  xr   [N,2]
// [4N, +4.8M)   partial [NR*NG][RANGE*3]
// bucket path after partial: recs [NCH*NR][CAP] float2, counts[NCH*NR] int, flag int
// scan path after partial:   flag int

// One wave per node: coalesced float4 row load, butterfly reduce.
__global__ void node_transform(const float* __restrict__ x,
                               const float* __restrict__ Wl, const float* __restrict__ bl,
                               const float* __restrict__ Wr, const float* __restrict__ br,
                               float* __restrict__ xl, float* __restrict__ xr) {
    int wave = (blockIdx.x * blockDim.x + threadIdx.x) >> 6;
    int lane = threadIdx.x & 63;
    if (wave >= N_NODES) return;
    const float4 xv  = *reinterpret_cast<const float4*>(x + (size_t)wave * D_IN + lane * 4);
    const float4 wlA = *reinterpret_cast<const float4*>(Wl + lane * 8);
    const float4 wlB = *reinterpret_cast<const float4*>(Wl + lane * 8 + 4);
    const float4 wrA = *reinterpret_cast<const float4*>(Wr + lane * 8);
    const float4 wrB = *reinterpret_cast<const float4*>(Wr + lane * 8 + 4);
    float sl0 = xv.x*wlA.x + xv.y*wlA.z + xv.z*wlB.x + xv.w*wlB.z;
    float sl1 = xv.x*wlA.y + xv.y*wlA.w + xv.z*wlB.y + xv.w*wlB.w;
    float sr0 = xv.x*wrA.x + xv.y*wrA.z + xv.z*wrB.x + xv.w*wrB.z;
    float sr1 = xv.x*wrA.y + xv.y*wrA.w + xv.z*wrB.y + xv.w*wrB.w;
    #pragma unroll
    for (int o = 32; o > 0; o >>= 1) {
        sl0 += __shfl_xor(sl0, o);
        sl1 += __shfl_xor(sl1, o);
        sr0 += __shfl_xor(sr0, o);
        sr1 += __shfl_xor(sr1, o);
    }
    if (lane == 0) {
        xl[2*wave]   = sl0 + bl[0];
        xl[2*wave+1] = sl1 + bl[1];
        xr[2*wave]   = sr0 + br[0];
        xr[2*wave+1] = sr1 + br[1];
    }
}

// Detect int64 vs int32 edge_index (int64 values < 2^17 => all odd words zero).
__global__ void detect_dtype(const int* __restrict__ ei32, int* __restrict__ flag) {
    int lane = threadIdx.x;  // 64 threads
    int v = ei32[2 * lane + 1];
    unsigned long long nz = __ballot(v != 0);
    if (lane == 0) *flag = (nz == 0ull) ? 1 : 0;
}

// ---------------- bucket path ----------------

// Pass B: pure streaming, no gathers, no math. Pack {src|li<<17, ea} into
// per-(chunk,range) segment via LDS slot counter. 4-wide vectorized loads.
__device__ __forceinline__ void bucket_one(int src, int tgt, float ea,
                                           float2* __restrict__ recs,
                                           int* __restrict__ cnt, int c) {
    const int r  = tgt / RANGE;
    const int li = tgt - r * RANGE;           // < 6250 -> 13 bits
    const int slot = atomicAdd(&cnt[r], 1);
    if (slot < CAP) {
        float2 rec;
        rec.x = __uint_as_float((unsigned)src | ((unsigned)li << 17));
        rec.y = ea;
        recs[(size_t)(c * NR + r) * CAP + slot] = rec;
    }
}

template <bool IS64>
__device__ __forceinline__ void bucket_loop(const void* __restrict__ ei,
                                            const float* __restrict__ eattr,
                                            float2* __restrict__ recs,
                                            int* __restrict__ cnt, int c) {
    const int base = c * CHE;
    const int end  = base + CHE;
    for (int j = 0; j < CHE; j += BBLK * 4) {
        const int e0 = base + j + (int)threadIdx.x * 4;
        if (e0 + 4 <= end) {
            int4 sv, tv;
            if (IS64) {
                const int4* ps = (const int4*)((const long long*)ei + e0);
                int4 a = ps[0], b = ps[1];
                sv = make_int4(a.x, a.z, b.x, b.z);
                const int4* pt = (const int4*)((const long long*)ei + N_EDGES + e0);
                int4 cc = pt[0], dd = pt[1];
                tv = make_int4(cc.x, cc.z, dd.x, dd.z);
            } else {
                sv = *(const int4*)((const int*)ei + e0);
                tv = *(const int4*)((const int*)ei + N_EDGES + e0);
            }
            const float4 ev = *(const float4*)(eattr + e0);
            bucket_one(sv.x, tv.x, ev.x, recs, cnt, c);
            bucket_one(sv.y, tv.y, ev.y, recs, cnt, c);
            bucket_one(sv.z, tv.z, ev.z, recs, cnt, c);
            bucket_one(sv.w, tv.w, ev.w, recs, cnt, c);
        } else if (e0 < end) {
            for (int e = e0; e < end && e < e0 + 4; ++e) {
                int src, tgt;
                if (IS64) { src = (int)((const long long*)ei)[e]; tgt = (int)((const long long*)ei)[N_EDGES + e]; }
                else      { src = ((const int*)ei)[e];            tgt = ((const int*)ei)[N_EDGES + e]; }
                bucket_one(src, tgt, eattr[e], recs, cnt, c);
            }
        }
    }
}

__global__ __launch_bounds__(BBLK) void bucket_pass(const void* __restrict__ ei,
                                                    const float* __restrict__ eattr,
                                                    float2* __restrict__ recs,
                                                    int* __restrict__ counts,
                                                    const int* __restrict__ flag) {
    __shared__ int cnt[NR];
    const int c = blockIdx.x;
    if (threadIdx.x < NR) cnt[threadIdx.x] = 0;
    __syncthreads();
    if (*flag) bucket_loop<true >(ei, eattr, recs, cnt, c);
    else       bucket_loop<false>(ei, eattr, recs, cnt, c);
    __syncthreads();
    if (threadIdx.x < NR) {
        int v = cnt[threadIdx.x];
        counts[c * NR + threadIdx.x] = v < CAP ? v : CAP;
    }
}

// Pass C: claim/winner accumulation, 2 recs/thread/batch (float4 pair),
// 2-deep record prefetch + 1-deep xs prefetch, 2 barriers/batch
// (loser atomics deferred into the NEXT batch's phase A).
__global__ __launch_bounds__(CBLK) void gather_accum(const float2* __restrict__ recs,
                                                     const int* __restrict__ counts,
                                                     const float* __restrict__ xl,
                                                     const float* __restrict__ xr,
                                                     const float* __restrict__ We,
                                                     const float* __restrict__ att,
                                                     float* __restrict__ partial) {
    __shared__ float  acc[RANGE * 3];   // 73.2 KB
    __shared__ float2 xrs[RANGE];       // 48.8 KB
    __shared__ int    tag[RANGE];       // 24.4 KB
    __shared__ int    s_n[CPG];
    const int r = blockIdx.x & (NR - 1);
    const int g = blockIdx.x >> 4;
    const int lo = r * RANGE;
    for (int i = threadIdx.x; i < RANGE * 3; i += CBLK) acc[i] = 0.f;
    for (int i = threadIdx.x; i < RANGE; i += CBLK) xrs[i] = ((const float2*)xr)[lo + i];
    for (int i = threadIdx.x; i < CPG; i += CBLK) s_n[i] = counts[(g * CPG + i) * NR + r];
    __syncthreads();
    const float we0 = We[0], we1 = We[1];
    const float a0 = att[0], a1 = att[1];
    const float2* xl2 = (const float2*)xl;
    const int c0 = g * CPG;
    const int tid = threadIdx.x;

    // pair fetch: pidx in [0, PFLAT); vmask bit0/bit1 = rec0/rec1 valid
    auto fetch_pair = [&](int pidx, unsigned& vm) -> float4 {
        float4 out = make_float4(0.f, 0.f, 0.f, 0.f);
        vm = 0u;
        if (pidx < PFLAT) {
            const int cc = pidx / HALFCAP;
            const int i  = pidx - cc * HALFCAP;
            const int n  = s_n[cc];
            if (2 * i < n) {
                const float2* seg = recs + (size_t)((c0 + cc) * NR + r) * CAP;
                out = ((const float4*)seg)[i];
                vm = (2 * i + 1 < n) ? 3u : 1u;
            }
        }
        return out;
    };

    // prologue: batch 0 pair + its xs; batch 1 pair
    unsigned vCur, vNxt, vFly;
    float4 curP = fetch_pair(tid, vCur);
    float4 nxtP = fetch_pair(CBLK + tid, vNxt);
    float2 xsA0 = make_float2(0.f, 0.f), xsA1 = make_float2(0.f, 0.f);
    if (vCur & 1u) xsA0 = xl2[__float_as_uint(curP.x) & 0x1FFFF];
    if (vCur & 2u) xsA1 = xl2[__float_as_uint(curP.z) & 0x1FFFF];

    // deferred losers
    bool d0 = false, d1 = false;
    int  dl0 = 0, dl1 = 0;
    float dc00 = 0.f, dc01 = 0.f, de0 = 0.f, dc10 = 0.f, dc11 = 0.f, de1 = 0.f;

    for (int b = 0; b < NB; ++b) {
        // issue batch b+2 pair and batch b+1 xs (hidden under this batch)
        float4 flyP = fetch_pair((b + 2) * CBLK + tid, vFly);
        float2 xsB0 = make_float2(0.f, 0.f), xsB1 = make_float2(0.f, 0.f);
        if (vNxt & 1u) xsB0 = xl2[__float_as_uint(nxtP.x) & 0x1FFFF];
        if (vNxt & 2u) xsB1 = xl2[__float_as_uint(nxtP.z) & 0x1FFFF];

        // ---- phase A: compute + claim; drain previous batch's losers ----
        const bool h0 = (vCur & 1u) != 0u, h1 = (vCur & 2u) != 0u;
        int li0 = 0, li1 = 0;
        float ex0 = 0.f, cv00 = 0.f, cv01 = 0.f;
        float ex1 = 0.f, cv10 = 0.f, cv11 = 0.f;
        if (h0) {
            const unsigned p = __float_as_uint(curP.x);
            li0 = p >> 17;
            const float2 xt = xrs[li0];
            float m0 = xsA0.x + xt.x + curP.y * we0;
            float m1 = xsA0.y + xt.y + curP.y * we1;
            m0 = m0 > 0.f ? m0 : NEG_SLOPE * m0;
            m1 = m1 > 0.f ? m1 : NEG_SLOPE * m1;
            ex0  = __expf(m0 * a0 + m1 * a1);
            cv00 = ex0 * xsA0.x;
            cv01 = ex0 * xsA0.y;
            tag[li0] = tid;                      // claim (non-atomic)
        }
        if (h1) {
            const unsigned p = __float_as_uint(curP.z);
            li1 = p >> 17;
            const float2 xt = xrs[li1];
            float m0 = xsA1.x + xt.x + curP.w * we0;
            float m1 = xsA1.y + xt.y + curP.w * we1;
            m0 = m0 > 0.f ? m0 : NEG_SLOPE * m0;
            m1 = m1 > 0.f ? m1 : NEG_SLOPE * m1;
            ex1  = __expf(m0 * a0 + m1 * a1);
            cv10 = ex1 * xsA1.x;
            cv11 = ex1 * xsA1.y;
            tag[li1] = tid;                      // claim
        }
        // deferred losers from previous batch (acc only; tag untouched)
        if (d0) {
            float* bp = acc + dl0 * 3;
            atomicAdd(bp + 0, dc00); atomicAdd(bp + 1, dc01); atomicAdd(bp + 2, de0);
            d0 = false;
        }
        if (d1) {
            float* bp = acc + dl1 * 3;
            atomicAdd(bp + 0, dc10); atomicAdd(bp + 1, dc11); atomicAdd(bp + 2, de1);
            d1 = false;
        }
        __syncthreads();
        // ---- phase B: winners plain-RMW; losers deferred ----
        if (h0) {
            if (tag[li0] == tid) {
                float* bp = acc + li0 * 3;
                bp[0] += cv00; bp[1] += cv01; bp[2] += ex0;
            } else {
                d0 = true; dl0 = li0; dc00 = cv00; dc01 = cv01; de0 = ex0;
            }
        }
        if (h1) {
            if (tag[li1] == tid) {
                float* bp = acc + li1 * 3;
                bp[0] += cv10; bp[1] += cv11; bp[2] += ex1;
            } else {
                d1 = true; dl1 = li1; dc10 = cv10; dc11 = cv11; de1 = ex1;
            }
        }
        __syncthreads();
        // rotate pipeline
        curP = nxtP; vCur = vNxt; xsA0 = xsB0; xsA1 = xsB1;
        nxtP = flyP; vNxt = vFly;
    }
    // flush last batch's losers (winners fenced by final barrier above)
    if (d0) {
        float* bp = acc + dl0 * 3;
        atomicAdd(bp + 0, dc00); atomicAdd(bp + 1, dc01); atomicAdd(bp + 2, de0);
    }
    if (d1) {
        float* bp = acc + dl1 * 3;
        atomicAdd(bp + 0, dc10); atomicAdd(bp + 1, dc11); atomicAdd(bp + 2, de1);
    }
    __syncthreads();

    float* dst = partial + (size_t)(r * NG + g) * (RANGE * 3);
    for (int i = threadIdx.x; i < RANGE * 3; i += CBLK) dst[i] = acc[i];
}

// ---------------- fallback scan path ----------------
template <bool IS64>
__device__ __forceinline__ void scan_loop(const void* __restrict__ ei,
                                          const float* __restrict__ eattr,
                                          const float2* __restrict__ xl2,
                                          const float2* __restrict__ xr2,
                                          float we0, float we1, float a0, float a1,
                                          int lo, int eBeg, int eEnd,
                                          float* __restrict__ acc) {
    for (int e = eBeg + (int)threadIdx.x; e < eEnd; e += CBLK) {
        int tgt;
        if (IS64) tgt = (int)((const long long*)ei)[N_EDGES + e];
        else      tgt = ((const int*)ei)[N_EDGES + e];
        unsigned li = (unsigned)(tgt - lo);
        if (li < RANGE) {
            int src;
            if (IS64) src = (int)((const long long*)ei)[e];
            else      src = ((const int*)ei)[e];
            const float ea = eattr[e];
            const float2 xs = xl2[src];
            const float2 xt = xr2[tgt];
            float m0 = xs.x + xt.x + ea * we0;
            float m1 = xs.y + xt.y + ea * we1;
            m0 = m0 > 0.f ? m0 : NEG_SLOPE * m0;
            m1 = m1 > 0.f ? m1 : NEG_SLOPE * m1;
            const float ex = __expf(m0 * a0 + m1 * a1);
            float* b = acc + li * 3u;
            atomicAdd(b + 0, ex * xs.x);
            atomicAdd(b + 1, ex * xs.y);
            atomicAdd(b + 2, ex);
        }
    }
}

__global__ __launch_bounds__(CBLK) void edge_scan(const void* __restrict__ ei,
                                                  const float* __restrict__ eattr,
                                                  const float* __restrict__ xl,
                                                  const float* __restrict__ xr,
                                                  const float* __restrict__ We,
                                                  const float* __restrict__ att,
                                                  float* __restrict__ partial,
                                                  const int* __restrict__ flag) {
    __shared__ float acc[RANGE * 3];
    const int r = blockIdx.x & (NR - 1);
    const int g = blockIdx.x >> 4;          // 16 chunks
    for (int i = threadIdx.x; i < RANGE * 3; i += CBLK) acc[i] = 0.f;
    __syncthreads();
    const int lo = r * RANGE;
    const int eBeg = g * FCHE, eEnd = eBeg + FCHE;
    const float we0 = We[0], we1 = We[1];
    const float a0 = att[0], a1 = att[1];
    if (*flag)
        scan_loop<true >(ei, eattr, (const float2*)xl, (const float2*)xr, we0, we1, a0, a1, lo, eBeg, eEnd, acc);
    else
        scan_loop<false>(ei, eattr, (const float2*)xl, (const float2*)xr, we0, we1, a0, a1, lo, eBeg, eEnd, acc);
    __syncthreads();
    float* dst = partial + (size_t)(r * NG + g) * (RANGE * 3);
    for (int i = threadIdx.x; i < RANGE * 3; i += CBLK) dst[i] = acc[i];
}
// ---------------------------------------------------------------------

// Sum the NG group-partials per node, normalize, add bias.
__global__ void reduce_partials(const float* __restrict__ partial,
                                const float* __restrict__ bias, float* __restrict__ out) {
    int i = blockIdx.x * blockDim.x + threadIdx.x;
    if (i >= N_NODES) return;
    const int r = i / RANGE;
    const int li = i - r * RANGE;
    float n0 = 0.f, n1 = 0.f, d = 0.f;
    #pragma unroll 4
    for (int g = 0; g < NG; ++g) {
        const float* p = partial + (size_t)(r * NG + g) * (RANGE * 3) + (size_t)li * 3;
        n0 += p[0]; n1 += p[1]; d += p[2];
    }
    d += 1e-16f;
    float2 o;
    o.x = n0 / d + bias[0];
    o.y = n1 / d + bias[1];
    ((float2*)out)[i] = o;
}

// last-resort atomic path
__global__ void edge_pass_atomic(const void* __restrict__ ei,
                                 const float* __restrict__ eattr,
                                 const float* __restrict__ xl, const float* __restrict__ xr,
                                 const float* __restrict__ We, const float* __restrict__ att,
                                 float* __restrict__ acc4, const int* __restrict__ flag) {
    const int is64 = *flag;
    const float we0 = We[0], we1 = We[1];
    const float a0 = att[0], a1 = att[1];
    const int stride = gridDim.x * blockDim.x;
    for (int e = blockIdx.x * blockDim.x + threadIdx.x; e < N_EDGES; e += stride) {
        int src, tgt;
        if (is64) { src = (int)((const long long*)ei)[e]; tgt = (int)((const long long*)ei)[N_EDGES + e]; }
        else      { src = ((const int*)ei)[e];            tgt = ((const int*)ei)[N_EDGES + e]; }
        const float ea = eattr[e];
        const float2 xs = ((const float2*)xl)[src];
        const float2 xt = ((const float2*)xr)[tgt];
        float m0 = xs.x + xt.x + ea * we0;
        float m1 = xs.y + xt.y + ea * we1;
        m0 = m0 > 0.f ? m0 : NEG_SLOPE * m0;
        m1 = m1 > 0.f ? m1 : NEG_SLOPE * m1;
        const float ex = __expf(m0 * a0 + m1 * a1);
        float* b = acc4 + (size_t)tgt * 4;
        atomicAdd(b + 0, ex * xs.x);
        atomicAdd(b + 1, ex * xs.y);
        atomicAdd(b + 2, ex);
    }
}

__global__ void finalize4(const float* __restrict__ acc4,
                          const float* __restrict__ bias, float* __restrict__ out) {
    int i = blockIdx.x * blockDim.x + threadIdx.x;
    if (i >= N_NODES) return;
    const float4 a = ((const float4*)acc4)[i];
    const float d = a.z + 1e-16f;
    float2 o;
    o.x = a.x / d + bias[0];
    o.y = a.y / d + bias[1];
    ((float2*)out)[i] = o;
}

extern "C" void kernel_launch(void* const* d_in, const int* in_sizes, int n_in,
                              void* d_out, int out_size, void* d_ws, size_t ws_size,
                              hipStream_t stream) {
    const float* x    = (const float*)d_in[0];
    const void*  ei   = d_in[1];
    const float* ea   = (const float*)d_in[2];
    const float* Wl   = (const float*)d_in[3];
    const float* bl   = (const float*)d_in[4];
    const float* Wr   = (const float*)d_in[5];
    const float* br   = (const float*)d_in[6];
    const float* We   = (const float*)d_in[7];
    const float* att  = (const float*)d_in[8];
    const float* bias = (const float*)d_in[9];

    float* ws      = (float*)d_ws;
    float* xl      = ws;
    float* xr      = ws + 2 * N_NODES;
    float* partial = ws + 4 * N_NODES;                       // [NR*NG][RANGE*3]
    const size_t partial_floats = (size_t)NR * NG * RANGE * 3;
    float* recs_f  = partial + partial_floats;               // [NCH*NR][CAP] float2
    const size_t recs_floats = (size_t)NCH * NR * CAP * 2;
    int*   counts  = (int*)(recs_f + recs_floats);           // [NCH*NR]

    const size_t need_bucket = (4 * (size_t)N_NODES + partial_floats + recs_floats
                                + (size_t)NCH * NR + 16) * sizeof(float);
    const size_t need_scan   = (4 * (size_t)N_NODES + partial_floats + 16) * sizeof(float);

    node_transform<<<(N_NODES * 64) / 256, 256, 0, stream>>>(x, Wl, bl, Wr, br, xl, xr);

    if (ws_size >= need_bucket) {
        int* flag = counts + (size_t)NCH * NR;
        detect_dtype<<<1, 64, 0, stream>>>((const int*)ei, flag);
        bucket_pass<<<NCH, BBLK, 0, stream>>>(ei, ea, (float2*)recs_f, counts, flag);
        gather_accum<<<NR * NG, CBLK, 0, stream>>>((const float2*)recs_f, counts,
                                                   xl, xr, We, att, partial);
        reduce_partials<<<(N_NODES + 255) / 256, 256, 0, stream>>>(partial, bias, (float*)d_out);
    } else if (ws_size >= need_scan) {
        int* flag = (int*)(partial + partial_floats);
        detect_dtype<<<1, 64, 0, stream>>>((const int*)ei, flag);
        edge_scan<<<NR * NG, CBLK, 0, stream>>>(ei, ea, xl, xr, We, att, partial, flag);
        reduce_partials<<<(N_NODES + 255) / 256, 256, 0, stream>>>(partial, bias, (float*)d_out);
    } else {
        float* acc4 = ws + 4 * N_NODES;
        int* flag = (int*)(acc4 + 4 * (size_t)N_NODES);
        hipMemsetAsync(acc4, 0, (size_t)N_NODES * 4 * sizeof(float), stream);
        detect_dtype<<<1, 64, 0, stream>>>((const int*)ei, flag);
        edge_pass_atomic<<<4096, 256, 0, stream>>>(ei, ea, xl, xr, We, att, acc4, flag);
        finalize4<<<(N_NODES + 255) / 256, 256, 0, stream>>>(acc4, bias, (float*)d_out);
    }
}